// Round 1
// 372.005 us; speedup vs baseline: 1.0543x; 1.0543x over previous
//
#include <hip/hip_runtime.h>
#include <hip/hip_bf16.h>

// R23: GRU rewritten around the real bottleneck: R22 was L2-BW-bound
// (each WG re-streamed the full 393KB W_hh from L2 every timestep:
// 6.44GB/185.7us = 34.7 TB/s = the L2 ceiling; VGPR_Count=128 proves wfrag
// was never register-resident). New GRU: 128 WGs x 256 thr (1 wave/SIMD,
// 512-reg unified budget) -> W_hh truly register-resident (12 tiles/wave,
// 384 regs + 48 acc). Tile mapping n(ct)=g*256+j*64+16wv+l15 plus real rows
// at A-rows {0,4,8,12} puts each row's (r,z,n) gh triple in reg 0 of every
// lane -> gates fully in-register, gh LDS array + scatter + one barrier
// eliminated. h16 double-buffered -> single lgkm-only barrier per step.
// MLP unchanged (proven R18 shape).

typedef __bf16 bf16_t;
typedef __bf16 bf16x2 __attribute__((ext_vector_type(2)));
typedef __bf16 bf16x8 __attribute__((ext_vector_type(8)));
typedef float f32x4 __attribute__((ext_vector_type(4)));

#define MFMA16(a, b, c) __builtin_amdgcn_mfma_f32_16x16x32_bf16(a, b, c, 0, 0, 0)

#define EMB 256
#define TSTEPS 128
#define OUTD 64

#define HS_OFF   0u           // bf16 65536x256 = 33,554,432
#define H0_OFF   33554432u    // f32 512x256   = 524,288
#define WHH_OFF  34078720u    // bf16 768x256  = 393,216
#define W1_OFF   34471936u    // bf16 512x256  = 262,144
#define W2_OFF   34734080u    // bf16 512x512  = 524,288
#define W3_OFF   35258368u    // bf16 512x512  = 524,288
#define MUW_OFF  35782656u    // bf16 64x512   = 65,536

__device__ __forceinline__ float rcpf(float x){ return __builtin_amdgcn_rcpf(x); }
__device__ __forceinline__ void lds_barrier() {
  asm volatile("s_waitcnt lgkmcnt(0)\n\ts_barrier" ::: "memory");
}

// ---------------------------------------------------------------------------
__global__ __launch_bounds__(256) void convert_kernel(
    const float* __restrict__ whh, const float* __restrict__ w1,
    const float* __restrict__ w2, const float* __restrict__ w3,
    const float* __restrict__ muw, char* __restrict__ ws)
{
  const int g = blockIdx.x * 256 + threadIdx.x;
  const int G = gridDim.x * 256;
  bf16_t* d;
  d = (bf16_t*)(ws + WHH_OFF); for (int i = g; i < 196608; i += G) d[i] = (bf16_t)whh[i];
  d = (bf16_t*)(ws + W1_OFF);  for (int i = g; i < 131072; i += G) d[i] = (bf16_t)w1[i];
  d = (bf16_t*)(ws + W2_OFF);  for (int i = g; i < 262144; i += G) d[i] = (bf16_t)w2[i];
  d = (bf16_t*)(ws + W3_OFF);  for (int i = g; i < 262144; i += G) d[i] = (bf16_t)w3[i];
  d = (bf16_t*)(ws + MUW_OFF); for (int i = g; i < 32768;  i += G) d[i] = (bf16_t)muw[i];
}

// ---------------------------------------------------------------------------
__global__ __launch_bounds__(256) void emb_kernel(
    const float* __restrict__ z_t, const float* __restrict__ z_g,
    const float* __restrict__ w_emb, float* __restrict__ h0)
{
  __shared__ float zrow[128];
  const int bw = blockIdx.x, tid = threadIdx.x;
  if (tid < 128)
    zrow[tid] = (tid < 64) ? z_t[bw * 64 + tid] : z_g[(bw >> 4) * 64 + (tid - 64)];
  __syncthreads();
  const float4* wp = reinterpret_cast<const float4*>(w_emb + (size_t)tid * 128);
  float s = 0.f;
#pragma unroll
  for (int k4 = 0; k4 < 32; ++k4) {
    const float4 w = wp[k4];
    s += zrow[k4 * 4 + 0] * w.x + zrow[k4 * 4 + 1] * w.y
       + zrow[k4 * 4 + 2] * w.z + zrow[k4 * 4 + 3] * w.w;
  }
  h0[(size_t)bw * 256 + tid] = s;
}

// ---------------------------------------------------------------------------
// GRU: 128 WGs x 256 thr (4 waves, 1 wave/SIMD). 4 rows/WG.
// Wave wv owns gh cols n(ct) = (ct>>2)*256 + (ct&3)*64 + 16*wv + l15,
// ct=0..11 (so each thread's acc[j], acc[4+j], acc[8+j] are the r/z/n gh
// values for row=quad, col=c0+j*64). Real batch rows live at A-rows
// {0,4,8,12} => C row m=4*quad lands in reg 0 of every lane. Gates are
// computed entirely in registers; single lgkm barrier per step; h16 is
// double-buffered so write(t) never races read(t).
// ---------------------------------------------------------------------------
__global__ __launch_bounds__(256, 1) void gru_kernel(
    const float* __restrict__ h0, const bf16_t* __restrict__ w_hh,
    const float* __restrict__ b_ih, const float* __restrict__ b_hh,
    bf16_t* __restrict__ hs)
{
  __shared__ __align__(16) bf16_t h16[2][16][264];

  const int tid  = threadIdx.x;
  const int wv   = tid >> 6;      // 0..3
  const int lane = tid & 63;
  const int l15  = lane & 15;
  const int quad = lane >> 4;     // 0..3 == batch row within WG
  const int bw0  = blockIdx.x * 4;
  const int c0   = wv * 16 + l15; // 0..63

  // register-resident W_hh: 12 col-tiles per wave, 8 k-frags each
  bf16x8 wfrag[12][8];
#pragma unroll
  for (int ct = 0; ct < 12; ++ct) {
    const int n = (ct >> 2) * 256 + (ct & 3) * 64 + c0;
#pragma unroll
    for (int kk = 0; kk < 8; ++kk)
      wfrag[ct][kk] = *reinterpret_cast<const bf16x8*>(
          w_hh + (size_t)n * 256 + kk * 32 + quad * 8);
  }

  // per-thread gate state: row = quad, cols c0 + j*64 (j=0..3)
  float br[4], bz[4], bin[4], bhn[4], hm[4];
#pragma unroll
  for (int j = 0; j < 4; ++j) {
    const int c = c0 + j * 64;
    br[j]  = b_ih[c]       + b_hh[c];
    bz[j]  = b_ih[256 + c] + b_hh[256 + c];
    bin[j] = b_ih[512 + c];
    bhn[j] = b_hh[512 + c];
    hm[j]  = h0[(size_t)(bw0 + quad) * 256 + c];
  }

  // zero both buffers (padding rows must be exactly 0), then seed buf 0
  {
    bf16x8 zv;
#pragma unroll
    for (int e = 0; e < 8; ++e) zv[e] = (bf16_t)0.f;
    for (int i = tid; i < 1056; i += 256)   // 2*16*264/8
      reinterpret_cast<bf16x8*>(h16)[i] = zv;
  }
  __syncthreads();
#pragma unroll
  for (int j = 0; j < 4; ++j)
    h16[0][quad * 4][c0 + j * 64] = (bf16_t)hm[j];
  __syncthreads();

  bf16_t* hsp = hs + ((size_t)(bw0 + quad) * TSTEPS) * EMB + c0;

#pragma unroll 1
  for (int t = 0; t < TSTEPS; ++t) {
    const bf16_t (*hr)[264] = h16[t & 1];
    bf16_t (*hw)[264] = h16[(t & 1) ^ 1];

    f32x4 acc[12] = {};
#pragma unroll
    for (int kk = 0; kk < 8; ++kk) {
      const bf16x8 a = *reinterpret_cast<const bf16x8*>(&hr[l15][kk * 32 + quad * 8]);
#pragma unroll
      for (int ct = 0; ct < 12; ++ct)
        acc[ct] = MFMA16(a, wfrag[ct][kk], acc[ct]);
    }

    // gates fully in-register: reg 0 of each acc is the real row (m=4*quad)
#pragma unroll
    for (int j = 0; j < 4; ++j) {
      const float gr = acc[j][0]     + br[j];
      const float gz = acc[4 + j][0] + bz[j];
      const float gn = acc[8 + j][0] + bhn[j];
      const float rr = rcpf(1.f + __expf(-gr));
      const float zz = rcpf(1.f + __expf(-gz));
      const float pre = bin[j] + rr * gn;
      const float nn = 1.f - 2.f * rcpf(__expf(2.f * pre) + 1.f);
      hm[j] = nn + zz * (hm[j] - nn);
      const bf16_t nh = (bf16_t)hm[j];
      hw[quad * 4][c0 + j * 64] = nh;
      hsp[(size_t)t * EMB + j * 64] = nh;
    }
    lds_barrier();   // writes to hw drained; next step reads hw as hr
  }
}

// ---------------------------------------------------------------------------
// Fused MLP: 512 WGs x 512 thr (8 waves), 128 rows/WG (R18 proven shape).
// Wave wv owns cols [wv*64,+64) (4 ct) x 8 m-tiles.
// ---------------------------------------------------------------------------
template<int KC>
__device__ __forceinline__ void mlp_layer(
    const bf16_t* __restrict__ W, const float* __restrict__ bias,
    bf16_t (*act)[520], int wv, int l15, int quad)
{
  f32x4 acc[4][8] = {};
#pragma unroll 2
  for (int kc = 0; kc < KC; ++kc) {
#pragma unroll
    for (int kk = 0; kk < 4; ++kk) {
      bf16x8 wf[4];
#pragma unroll
      for (int ct = 0; ct < 4; ++ct)
        wf[ct] = *reinterpret_cast<const bf16x8*>(
            W + (size_t)(wv * 64 + ct * 16 + l15) * (KC * 128) + kc * 128 + kk * 32 + quad * 8);
#pragma unroll
      for (int mt = 0; mt < 8; ++mt) {
        bf16x8 a = *reinterpret_cast<const bf16x8*>(&act[mt * 16 + l15][kc * 128 + kk * 32 + quad * 8]);
#pragma unroll
        for (int ct = 0; ct < 4; ++ct)
          acc[ct][mt] = MFMA16(a, wf[ct], acc[ct][mt]);
      }
    }
  }
  __syncthreads();
#pragma unroll
  for (int ct = 0; ct < 4; ++ct) {
    const int n = wv * 64 + ct * 16 + l15;
    const float b = bias[n];
#pragma unroll
    for (int mt = 0; mt < 8; ++mt)
#pragma unroll
      for (int r = 0; r < 4; ++r) {
        float x = acc[ct][mt][r] + b;
        x = (x > 0.f) ? x : (__expf(x) - 1.f);   // ELU
        act[mt * 16 + quad * 4 + r][n] = (bf16_t)x;
      }
  }
  __syncthreads();
}

__global__ __launch_bounds__(512, 2) void mlp_kernel(
    const bf16_t* __restrict__ hs,
    const bf16_t* __restrict__ w1, const float* __restrict__ b1,
    const bf16_t* __restrict__ w2, const float* __restrict__ b2,
    const bf16_t* __restrict__ w3, const float* __restrict__ b3,
    const bf16_t* __restrict__ muw, const float* __restrict__ mub,
    float* __restrict__ out)
{
  __shared__ __align__(16) bf16_t act[128][520];

  const int tid  = threadIdx.x;
  const int wv   = tid >> 6;
  const int lane = tid & 63;
  const int l15  = lane & 15;
  const int quad = lane >> 4;
  const size_t r0 = (size_t)blockIdx.x * 128;

  for (int v = tid; v < 128 * 32; v += 512) {
    const int rr = v >> 5, cc = v & 31;
    bf16x8 x = *reinterpret_cast<const bf16x8*>(hs + (r0 + rr) * EMB + cc * 8);
    *reinterpret_cast<bf16x8*>(&act[rr][cc * 8]) = x;
  }
  __syncthreads();

  mlp_layer<2>(w1, b1, act, wv, l15, quad);   // 256 -> 512
  mlp_layer<4>(w2, b2, act, wv, l15, quad);   // 512 -> 512
  mlp_layer<4>(w3, b3, act, wv, l15, quad);   // 512 -> 512

  // mu head: wave wv -> col-tile (wv&3), m-tiles (wv>>2)*4 .. +4
  f32x4 macc[4] = {};
  const int n   = (wv & 3) * 16 + l15;
  const int mtb = (wv >> 2) * 4;
#pragma unroll 1
  for (int kc = 0; kc < 4; ++kc) {
#pragma unroll
    for (int kk = 0; kk < 4; ++kk) {
      bf16x8 wf = *reinterpret_cast<const bf16x8*>(
          muw + (size_t)n * 512 + kc * 128 + kk * 32 + quad * 8);
#pragma unroll
      for (int i = 0; i < 4; ++i) {
        bf16x8 a = *reinterpret_cast<const bf16x8*>(
            &act[(mtb + i) * 16 + l15][kc * 128 + kk * 32 + quad * 8]);
        macc[i] = MFMA16(a, wf, macc[i]);
      }
    }
  }
  const float mb = mub[n];
#pragma unroll
  for (int i = 0; i < 4; ++i)
#pragma unroll
    for (int r = 0; r < 4; ++r)
      out[(r0 + (mtb + i) * 16 + quad * 4 + r) * OUTD + n] = macc[i][r] + mb;
}

// ---------------------------------------------------------------------------
extern "C" void kernel_launch(void* const* d_in, const int* in_sizes, int n_in,
                              void* d_out, int out_size, void* d_ws, size_t ws_size,
                              hipStream_t stream) {
  char* ws = (char*)d_ws;

  convert_kernel<<<256, 256, 0, stream>>>(
      (const float*)d_in[3], (const float*)d_in[6], (const float*)d_in[8],
      (const float*)d_in[10], (const float*)d_in[12], ws);

  emb_kernel<<<512, 256, 0, stream>>>(
      (const float*)d_in[0], (const float*)d_in[1], (const float*)d_in[2],
      (float*)(ws + H0_OFF));

  gru_kernel<<<128, 256, 0, stream>>>(
      (const float*)(ws + H0_OFF), (const bf16_t*)(ws + WHH_OFF),
      (const float*)d_in[4], (const float*)d_in[5],
      (bf16_t*)(ws + HS_OFF));

  mlp_kernel<<<512, 512, 0, stream>>>(
      (const bf16_t*)(ws + HS_OFF),
      (const bf16_t*)(ws + W1_OFF), (const float*)d_in[7],
      (const bf16_t*)(ws + W2_OFF), (const float*)d_in[9],
      (const bf16_t*)(ws + W3_OFF), (const float*)d_in[11],
      (const bf16_t*)(ws + MUW_OFF), (const float*)d_in[13],
      (float*)d_out);
}

// Round 3
// 370.012 us; speedup vs baseline: 1.0600x; 1.0054x over previous
//
#include <hip/hip_runtime.h>
#include <hip/hip_bf16.h>

// R25: R24 (AGPR-pinned W_hh, zero L2 traffic in t-loop) + MFMA hazard fences.
// R24 failed correctness (absmax 0.13) because inline-asm MFMA bypasses the
// compiler's software-managed hazard insertion: (a) MFMA-write-D -> VALU-read-D
// needs up to 18 wait states and the scheduler was free to place gate VALU
// inside that window; (b) VALU zero-init of acc -> asm MFMA SrcC read needs 2.
// Fix: sched_barrier(0) pins + explicit s_nop padding at both boundaries of
// the asm MFMA block. ~20 cyc/step overhead (~2%).
// MLP unchanged (R18 proven shape).

typedef __bf16 bf16_t;
typedef __bf16 bf16x2 __attribute__((ext_vector_type(2)));
typedef __bf16 bf16x8 __attribute__((ext_vector_type(8)));
typedef float f32x4 __attribute__((ext_vector_type(4)));

#define MFMA16(a, b, c) __builtin_amdgcn_mfma_f32_16x16x32_bf16(a, b, c, 0, 0, 0)

#define EMB 256
#define TSTEPS 128
#define OUTD 64

#define HS_OFF   0u           // bf16 65536x256 = 33,554,432
#define H0_OFF   33554432u    // f32 512x256   = 524,288
#define WHH_OFF  34078720u    // bf16 768x256  = 393,216
#define W1_OFF   34471936u    // bf16 512x256  = 262,144
#define W2_OFF   34734080u    // bf16 512x512  = 524,288
#define W3_OFF   35258368u    // bf16 512x512  = 524,288
#define MUW_OFF  35782656u    // bf16 64x512   = 65,536

__device__ __forceinline__ float rcpf(float x){ return __builtin_amdgcn_rcpf(x); }
__device__ __forceinline__ void lds_barrier() {
  asm volatile("s_waitcnt lgkmcnt(0)\n\ts_barrier" ::: "memory");
}

// ---------------------------------------------------------------------------
__global__ __launch_bounds__(256) void convert_kernel(
    const float* __restrict__ whh, const float* __restrict__ w1,
    const float* __restrict__ w2, const float* __restrict__ w3,
    const float* __restrict__ muw, char* __restrict__ ws)
{
  const int g = blockIdx.x * 256 + threadIdx.x;
  const int G = gridDim.x * 256;
  bf16_t* d;
  d = (bf16_t*)(ws + WHH_OFF); for (int i = g; i < 196608; i += G) d[i] = (bf16_t)whh[i];
  d = (bf16_t*)(ws + W1_OFF);  for (int i = g; i < 131072; i += G) d[i] = (bf16_t)w1[i];
  d = (bf16_t*)(ws + W2_OFF);  for (int i = g; i < 262144; i += G) d[i] = (bf16_t)w2[i];
  d = (bf16_t*)(ws + W3_OFF);  for (int i = g; i < 262144; i += G) d[i] = (bf16_t)w3[i];
  d = (bf16_t*)(ws + MUW_OFF); for (int i = g; i < 32768;  i += G) d[i] = (bf16_t)muw[i];
}

// ---------------------------------------------------------------------------
__global__ __launch_bounds__(256) void emb_kernel(
    const float* __restrict__ z_t, const float* __restrict__ z_g,
    const float* __restrict__ w_emb, float* __restrict__ h0)
{
  __shared__ float zrow[128];
  const int bw = blockIdx.x, tid = threadIdx.x;
  if (tid < 128)
    zrow[tid] = (tid < 64) ? z_t[bw * 64 + tid] : z_g[(bw >> 4) * 64 + (tid - 64)];
  __syncthreads();
  const float4* wp = reinterpret_cast<const float4*>(w_emb + (size_t)tid * 128);
  float s = 0.f;
#pragma unroll
  for (int k4 = 0; k4 < 32; ++k4) {
    const float4 w = wp[k4];
    s += zrow[k4 * 4 + 0] * w.x + zrow[k4 * 4 + 1] * w.y
       + zrow[k4 * 4 + 2] * w.z + zrow[k4 * 4 + 3] * w.w;
  }
  h0[(size_t)bw * 256 + tid] = s;
}

// ---------------------------------------------------------------------------
// GRU: 128 WGs x 256 thr (4 waves, 1 wave/SIMD => 512-reg unified budget).
// 4 rows/WG at A-rows {0,4,8,12} so C row m=4*quad is reg 0 of every lane.
// Wave wv owns gh cols n(ct) = (ct>>2)*256 + (ct&3)*64 + 16*wv + l15.
// ct 0..7 (gates r,z): B-frags AGPR-pinned via inline-asm "a" constraint.
// ct 8..11 (gate n):   B-frags in arch VGPRs via the intrinsic.
// Hazard fences around the asm MFMA block (see header comment).
// ---------------------------------------------------------------------------
__global__ __launch_bounds__(256, 1) void gru_kernel(
    const float* __restrict__ h0, const bf16_t* __restrict__ w_hh,
    const float* __restrict__ b_ih, const float* __restrict__ b_hh,
    bf16_t* __restrict__ hs)
{
  __shared__ __align__(16) bf16_t h16[2][16][264];

  const int tid  = threadIdx.x;
  const int wv   = tid >> 6;      // 0..3
  const int lane = tid & 63;
  const int l15  = lane & 15;
  const int quad = lane >> 4;     // 0..3 == batch row within WG
  const int bw0  = blockIdx.x * 4;
  const int c0   = wv * 16 + l15; // 0..63

  // --- W_hh fragments ---
  // AGPR-pinned: gates r (ct 0..3) and z (ct 4..7) -> 64 frags = 256 AGPRs
  bf16x8 wA[8][8];
#pragma unroll
  for (int ct = 0; ct < 8; ++ct) {
    const int n = (ct >> 2) * 256 + (ct & 3) * 64 + c0;
#pragma unroll
    for (int kk = 0; kk < 8; ++kk)
      wA[ct][kk] = *reinterpret_cast<const bf16x8*>(
          w_hh + (size_t)n * 256 + kk * 32 + quad * 8);
  }
  // VGPR: gate n (cols 512 + j*64 + c0) -> 32 frags = 128 VGPRs
  bf16x8 wV[4][8];
#pragma unroll
  for (int j = 0; j < 4; ++j) {
    const int n = 512 + j * 64 + c0;
#pragma unroll
    for (int kk = 0; kk < 8; ++kk)
      wV[j][kk] = *reinterpret_cast<const bf16x8*>(
          w_hh + (size_t)n * 256 + kk * 32 + quad * 8);
  }

  // per-thread gate state: row = quad, cols c0 + j*64 (j=0..3)
  float br[4], bz[4], bin[4], bhn[4], hm[4];
#pragma unroll
  for (int j = 0; j < 4; ++j) {
    const int c = c0 + j * 64;
    br[j]  = b_ih[c]       + b_hh[c];
    bz[j]  = b_ih[256 + c] + b_hh[256 + c];
    bin[j] = b_ih[512 + c];
    bhn[j] = b_hh[512 + c];
    hm[j]  = h0[(size_t)(bw0 + quad) * 256 + c];
  }

  // zero both buffers (padding rows read by ds_read must be benign), seed buf0
  {
    bf16x8 zv;
#pragma unroll
    for (int e = 0; e < 8; ++e) zv[e] = (bf16_t)0.f;
    for (int i = tid; i < 1056; i += 256)   // 2*16*264/8
      reinterpret_cast<bf16x8*>(h16)[i] = zv;
  }
  __syncthreads();
#pragma unroll
  for (int j = 0; j < 4; ++j)
    h16[0][quad * 4][c0 + j * 64] = (bf16_t)hm[j];
  __syncthreads();

  bf16_t* hsp = hs + ((size_t)(bw0 + quad) * TSTEPS) * EMB + c0;

#pragma unroll 1
  for (int t = 0; t < TSTEPS; ++t) {
    const bf16_t (*hr)[264] = h16[t & 1];
    bf16_t (*hw)[264] = h16[(t & 1) ^ 1];

    // preload all 8 A-frags (pipelined ds_reads)
    bf16x8 a8[8];
#pragma unroll
    for (int kk = 0; kk < 8; ++kk)
      a8[kk] = *reinterpret_cast<const bf16x8*>(&hr[l15][kk * 32 + quad * 8]);

    f32x4 acc[12] = {};
    // fence: VALU zero-init of acc must be >=2 cycles before asm MFMA SrcC read
    __builtin_amdgcn_sched_barrier(0);
    asm volatile("s_nop 1" :::);

#pragma unroll
    for (int kk = 0; kk < 8; ++kk) {
#pragma unroll
      for (int ct = 0; ct < 8; ++ct)
        asm("v_mfma_f32_16x16x32_bf16 %0, %1, %2, %0"
            : "+v"(acc[ct]) : "v"(a8[kk]), "a"(wA[ct][kk]));
#pragma unroll
      for (int j = 0; j < 4; ++j)
        acc[8 + j] = MFMA16(a8[kk], wV[j][kk], acc[8 + j]);
    }

    // fence: asm MFMA write-D -> VALU read-D needs up to 18 wait states, and
    // the scheduler must not move gate VALU into that window.
    __builtin_amdgcn_sched_barrier(0);
    asm volatile("s_nop 7\n\ts_nop 7\n\ts_nop 1" :::);
    __builtin_amdgcn_sched_barrier(0);

    // gates fully in-register: reg 0 of each acc is the real row (m=4*quad)
#pragma unroll
    for (int j = 0; j < 4; ++j) {
      const float gr = acc[j][0]     + br[j];
      const float gz = acc[4 + j][0] + bz[j];
      const float gn = acc[8 + j][0] + bhn[j];
      const float rr = rcpf(1.f + __expf(-gr));
      const float zz = rcpf(1.f + __expf(-gz));
      const float pre = bin[j] + rr * gn;
      const float nn = 1.f - 2.f * rcpf(__expf(2.f * pre) + 1.f);
      hm[j] = nn + zz * (hm[j] - nn);
      const bf16_t nh = (bf16_t)hm[j];
      hw[quad * 4][c0 + j * 64] = nh;
      hsp[(size_t)t * EMB + j * 64] = nh;
    }
    lds_barrier();   // hw writes drained; next step reads hw as hr
  }
}

// ---------------------------------------------------------------------------
// Fused MLP: 512 WGs x 512 thr (8 waves), 128 rows/WG (R18 proven shape).
// Wave wv owns cols [wv*64,+64) (4 ct) x 8 m-tiles.
// ---------------------------------------------------------------------------
template<int KC>
__device__ __forceinline__ void mlp_layer(
    const bf16_t* __restrict__ W, const float* __restrict__ bias,
    bf16_t (*act)[520], int wv, int l15, int quad)
{
  f32x4 acc[4][8] = {};
#pragma unroll 2
  for (int kc = 0; kc < KC; ++kc) {
#pragma unroll
    for (int kk = 0; kk < 4; ++kk) {
      bf16x8 wf[4];
#pragma unroll
      for (int ct = 0; ct < 4; ++ct)
        wf[ct] = *reinterpret_cast<const bf16x8*>(
            W + (size_t)(wv * 64 + ct * 16 + l15) * (KC * 128) + kc * 128 + kk * 32 + quad * 8);
#pragma unroll
      for (int mt = 0; mt < 8; ++mt) {
        bf16x8 a = *reinterpret_cast<const bf16x8*>(&act[mt * 16 + l15][kc * 128 + kk * 32 + quad * 8]);
#pragma unroll
        for (int ct = 0; ct < 4; ++ct)
          acc[ct][mt] = MFMA16(a, wf[ct], acc[ct][mt]);
      }
    }
  }
  __syncthreads();
#pragma unroll
  for (int ct = 0; ct < 4; ++ct) {
    const int n = wv * 64 + ct * 16 + l15;
    const float b = bias[n];
#pragma unroll
    for (int mt = 0; mt < 8; ++mt)
#pragma unroll
      for (int r = 0; r < 4; ++r) {
        float x = acc[ct][mt][r] + b;
        x = (x > 0.f) ? x : (__expf(x) - 1.f);   // ELU
        act[mt * 16 + quad * 4 + r][n] = (bf16_t)x;
      }
  }
  __syncthreads();
}

__global__ __launch_bounds__(512, 2) void mlp_kernel(
    const bf16_t* __restrict__ hs,
    const bf16_t* __restrict__ w1, const float* __restrict__ b1,
    const bf16_t* __restrict__ w2, const float* __restrict__ b2,
    const bf16_t* __restrict__ w3, const float* __restrict__ b3,
    const bf16_t* __restrict__ muw, const float* __restrict__ mub,
    float* __restrict__ out)
{
  __shared__ __align__(16) bf16_t act[128][520];

  const int tid  = threadIdx.x;
  const int wv   = tid >> 6;
  const int lane = tid & 63;
  const int l15  = lane & 15;
  const int quad = lane >> 4;
  const size_t r0 = (size_t)blockIdx.x * 128;

  for (int v = tid; v < 128 * 32; v += 512) {
    const int rr = v >> 5, cc = v & 31;
    bf16x8 x = *reinterpret_cast<const bf16x8*>(hs + (r0 + rr) * EMB + cc * 8);
    *reinterpret_cast<bf16x8*>(&act[rr][cc * 8]) = x;
  }
  __syncthreads();

  mlp_layer<2>(w1, b1, act, wv, l15, quad);   // 256 -> 512
  mlp_layer<4>(w2, b2, act, wv, l15, quad);   // 512 -> 512
  mlp_layer<4>(w3, b3, act, wv, l15, quad);   // 512 -> 512

  // mu head: wave wv -> col-tile (wv&3), m-tiles (wv>>2)*4 .. +4
  f32x4 macc[4] = {};
  const int n   = (wv & 3) * 16 + l15;
  const int mtb = (wv >> 2) * 4;
#pragma unroll 1
  for (int kc = 0; kc < 4; ++kc) {
#pragma unroll
    for (int kk = 0; kk < 4; ++kk) {
      bf16x8 wf = *reinterpret_cast<const bf16x8*>(
          muw + (size_t)n * 512 + kc * 128 + kk * 32 + quad * 8);
#pragma unroll
      for (int i = 0; i < 4; ++i) {
        bf16x8 a = *reinterpret_cast<const bf16x8*>(
            &act[(mtb + i) * 16 + l15][kc * 128 + kk * 32 + quad * 8]);
        macc[i] = MFMA16(a, wf, macc[i]);
      }
    }
  }
  const float mb = mub[n];
#pragma unroll
  for (int i = 0; i < 4; ++i)
#pragma unroll
    for (int r = 0; r < 4; ++r)
      out[(r0 + (mtb + i) * 16 + quad * 4 + r) * OUTD + n] = macc[i][r] + mb;
}

// ---------------------------------------------------------------------------
extern "C" void kernel_launch(void* const* d_in, const int* in_sizes, int n_in,
                              void* d_out, int out_size, void* d_ws, size_t ws_size,
                              hipStream_t stream) {
  char* ws = (char*)d_ws;

  convert_kernel<<<256, 256, 0, stream>>>(
      (const float*)d_in[3], (const float*)d_in[6], (const float*)d_in[8],
      (const float*)d_in[10], (const float*)d_in[12], ws);

  emb_kernel<<<512, 256, 0, stream>>>(
      (const float*)d_in[0], (const float*)d_in[1], (const float*)d_in[2],
      (float*)(ws + H0_OFF));

  gru_kernel<<<128, 256, 0, stream>>>(
      (const float*)(ws + H0_OFF), (const bf16_t*)(ws + WHH_OFF),
      (const float*)d_in[4], (const float*)d_in[5],
      (bf16_t*)(ws + HS_OFF));

  mlp_kernel<<<512, 512, 0, stream>>>(
      (const bf16_t*)(ws + HS_OFF),
      (const bf16_t*)(ws + W1_OFF), (const float*)d_in[7],
      (const bf16_t*)(ws + W2_OFF), (const float*)d_in[9],
      (const bf16_t*)(ws + W3_OFF), (const float*)d_in[11],
      (const bf16_t*)(ws + MUW_OFF), (const float*)d_in[13],
      (float*)d_out);
}

// Round 4
// 348.494 us; speedup vs baseline: 1.1254x; 1.0617x over previous
//
#include <hip/hip_runtime.h>
#include <hip/hip_bf16.h>

// R26: MLP attack. R25 post-mortem: GRU is MFMA-pipe-occupancy-bound
// (per-SIMD pipe = ~19.4 cyc per 16x16x32 MFMA; 96 MFMAs/wave/step = 1862 cyc
// floor of the measured 3020) - near its single-WG structural floor; left
// byte-identical. MLP (~175us vs 43.5us pipe floor, VGPR_Count=124 = zero
// prefetch lookahead at 2 waves/SIMD) gets: (1) depth-1 double-buffered
// prefetch of weight fragments + per-iter A-frag preload (fully unrolled ->
// compile-time buffer indices); (2) fragment-ordered weight layout from
// convert_kernel so each wave's 1KB W-fragment is ONE coalesced
// global_load_dwordx4 (was 16 scattered 2KB-strided lines).

typedef __bf16 bf16_t;
typedef __bf16 bf16x2 __attribute__((ext_vector_type(2)));
typedef __bf16 bf16x8 __attribute__((ext_vector_type(8)));
typedef float f32x4 __attribute__((ext_vector_type(4)));

#define MFMA16(a, b, c) __builtin_amdgcn_mfma_f32_16x16x32_bf16(a, b, c, 0, 0, 0)

#define EMB 256
#define TSTEPS 128
#define OUTD 64

#define HS_OFF   0u           // bf16 65536x256 = 33,554,432
#define H0_OFF   33554432u    // f32 512x256   = 524,288
#define WHH_OFF  34078720u    // bf16 768x256  = 393,216
#define W1_OFF   34471936u    // bf16 512x256  = 262,144 (fragment-ordered)
#define W2_OFF   34734080u    // bf16 512x512  = 524,288 (fragment-ordered)
#define W3_OFF   35258368u    // bf16 512x512  = 524,288 (fragment-ordered)
#define MUW_OFF  35782656u    // bf16 64x512   = 65,536  (fragment-ordered)

__device__ __forceinline__ float rcpf(float x){ return __builtin_amdgcn_rcpf(x); }
__device__ __forceinline__ void lds_barrier() {
  asm volatile("s_waitcnt lgkmcnt(0)\n\ts_barrier" ::: "memory");
}

// ---------------------------------------------------------------------------
// Fragment layout: element (n, k) of an NxK weight, with n = nt*16 + l15,
// k = kc*128 + kk*32 + quad*8 + e, lane = quad*16 + l15, lives at
//   Wf[(((nt*KC + kc)*4 + kk) << 9) + lane*8 + e]
// so one wave's (nt,kc,kk) fragment is 1024 contiguous bytes, lane i at 16i.
// ---------------------------------------------------------------------------
template<int KC>
__device__ __forceinline__ void conv_frag(
    const float* __restrict__ src, bf16_t* __restrict__ dst,
    int NK, int g, int G)
{
  const int K = KC * 128;
  for (int i = g; i < NK; i += G) {
    const int e    = i & 7;
    const int lane = (i >> 3) & 63;
    const int kk   = (i >> 9) & 3;
    const int rem  = i >> 11;
    const int kc   = rem & (KC - 1);
    const int nt   = rem / KC;          // KC pow2 -> shift
    const int l15  = lane & 15, quad = lane >> 4;
    dst[i] = (bf16_t)src[(size_t)(nt * 16 + l15) * K + kc * 128 + kk * 32 + quad * 8 + e];
  }
}

__global__ __launch_bounds__(256) void convert_kernel(
    const float* __restrict__ whh, const float* __restrict__ w1,
    const float* __restrict__ w2, const float* __restrict__ w3,
    const float* __restrict__ muw, char* __restrict__ ws)
{
  const int g = blockIdx.x * 256 + threadIdx.x;
  const int G = gridDim.x * 256;
  bf16_t* d;
  d = (bf16_t*)(ws + WHH_OFF); for (int i = g; i < 196608; i += G) d[i] = (bf16_t)whh[i];
  conv_frag<2>(w1,  (bf16_t*)(ws + W1_OFF),  131072, g, G);
  conv_frag<4>(w2,  (bf16_t*)(ws + W2_OFF),  262144, g, G);
  conv_frag<4>(w3,  (bf16_t*)(ws + W3_OFF),  262144, g, G);
  conv_frag<4>(muw, (bf16_t*)(ws + MUW_OFF), 32768,  g, G);
}

// ---------------------------------------------------------------------------
__global__ __launch_bounds__(256) void emb_kernel(
    const float* __restrict__ z_t, const float* __restrict__ z_g,
    const float* __restrict__ w_emb, float* __restrict__ h0)
{
  __shared__ float zrow[128];
  const int bw = blockIdx.x, tid = threadIdx.x;
  if (tid < 128)
    zrow[tid] = (tid < 64) ? z_t[bw * 64 + tid] : z_g[(bw >> 4) * 64 + (tid - 64)];
  __syncthreads();
  const float4* wp = reinterpret_cast<const float4*>(w_emb + (size_t)tid * 128);
  float s = 0.f;
#pragma unroll
  for (int k4 = 0; k4 < 32; ++k4) {
    const float4 w = wp[k4];
    s += zrow[k4 * 4 + 0] * w.x + zrow[k4 * 4 + 1] * w.y
       + zrow[k4 * 4 + 2] * w.z + zrow[k4 * 4 + 3] * w.w;
  }
  h0[(size_t)bw * 256 + tid] = s;
}

// ---------------------------------------------------------------------------
// GRU: unchanged from R25 (AGPR-pinned W_hh + hazard fences). Near its
// structural floor: 96 MFMAs/wave/step x ~19.4 cyc per-SIMD pipe = 1862 cyc
// of the measured ~3020 cyc/step.
// ---------------------------------------------------------------------------
__global__ __launch_bounds__(256, 1) void gru_kernel(
    const float* __restrict__ h0, const bf16_t* __restrict__ w_hh,
    const float* __restrict__ b_ih, const float* __restrict__ b_hh,
    bf16_t* __restrict__ hs)
{
  __shared__ __align__(16) bf16_t h16[2][16][264];

  const int tid  = threadIdx.x;
  const int wv   = tid >> 6;      // 0..3
  const int lane = tid & 63;
  const int l15  = lane & 15;
  const int quad = lane >> 4;     // 0..3 == batch row within WG
  const int bw0  = blockIdx.x * 4;
  const int c0   = wv * 16 + l15; // 0..63

  // AGPR-pinned: gates r (ct 0..3) and z (ct 4..7) -> 64 frags = 256 AGPRs
  bf16x8 wA[8][8];
#pragma unroll
  for (int ct = 0; ct < 8; ++ct) {
    const int n = (ct >> 2) * 256 + (ct & 3) * 64 + c0;
#pragma unroll
    for (int kk = 0; kk < 8; ++kk)
      wA[ct][kk] = *reinterpret_cast<const bf16x8*>(
          w_hh + (size_t)n * 256 + kk * 32 + quad * 8);
  }
  // VGPR: gate n (cols 512 + j*64 + c0) -> 32 frags = 128 VGPRs
  bf16x8 wV[4][8];
#pragma unroll
  for (int j = 0; j < 4; ++j) {
    const int n = 512 + j * 64 + c0;
#pragma unroll
    for (int kk = 0; kk < 8; ++kk)
      wV[j][kk] = *reinterpret_cast<const bf16x8*>(
          w_hh + (size_t)n * 256 + kk * 32 + quad * 8);
  }

  float br[4], bz[4], bin[4], bhn[4], hm[4];
#pragma unroll
  for (int j = 0; j < 4; ++j) {
    const int c = c0 + j * 64;
    br[j]  = b_ih[c]       + b_hh[c];
    bz[j]  = b_ih[256 + c] + b_hh[256 + c];
    bin[j] = b_ih[512 + c];
    bhn[j] = b_hh[512 + c];
    hm[j]  = h0[(size_t)(bw0 + quad) * 256 + c];
  }

  {
    bf16x8 zv;
#pragma unroll
    for (int e = 0; e < 8; ++e) zv[e] = (bf16_t)0.f;
    for (int i = tid; i < 1056; i += 256)   // 2*16*264/8
      reinterpret_cast<bf16x8*>(h16)[i] = zv;
  }
  __syncthreads();
#pragma unroll
  for (int j = 0; j < 4; ++j)
    h16[0][quad * 4][c0 + j * 64] = (bf16_t)hm[j];
  __syncthreads();

  bf16_t* hsp = hs + ((size_t)(bw0 + quad) * TSTEPS) * EMB + c0;

#pragma unroll 1
  for (int t = 0; t < TSTEPS; ++t) {
    const bf16_t (*hr)[264] = h16[t & 1];
    bf16_t (*hw)[264] = h16[(t & 1) ^ 1];

    bf16x8 a8[8];
#pragma unroll
    for (int kk = 0; kk < 8; ++kk)
      a8[kk] = *reinterpret_cast<const bf16x8*>(&hr[l15][kk * 32 + quad * 8]);

    f32x4 acc[12] = {};
    __builtin_amdgcn_sched_barrier(0);
    asm volatile("s_nop 1" :::);

#pragma unroll
    for (int kk = 0; kk < 8; ++kk) {
#pragma unroll
      for (int ct = 0; ct < 8; ++ct)
        asm("v_mfma_f32_16x16x32_bf16 %0, %1, %2, %0"
            : "+v"(acc[ct]) : "v"(a8[kk]), "a"(wA[ct][kk]));
#pragma unroll
      for (int j = 0; j < 4; ++j)
        acc[8 + j] = MFMA16(a8[kk], wV[j][kk], acc[8 + j]);
    }

    __builtin_amdgcn_sched_barrier(0);
    asm volatile("s_nop 7\n\ts_nop 7\n\ts_nop 1" :::);
    __builtin_amdgcn_sched_barrier(0);

#pragma unroll
    for (int j = 0; j < 4; ++j) {
      const float gr = acc[j][0]     + br[j];
      const float gz = acc[4 + j][0] + bz[j];
      const float gn = acc[8 + j][0] + bhn[j];
      const float rr = rcpf(1.f + __expf(-gr));
      const float zz = rcpf(1.f + __expf(-gz));
      const float pre = bin[j] + rr * gn;
      const float nn = 1.f - 2.f * rcpf(__expf(2.f * pre) + 1.f);
      hm[j] = nn + zz * (hm[j] - nn);
      const bf16_t nh = (bf16_t)hm[j];
      hw[quad * 4][c0 + j * 64] = nh;
      hsp[(size_t)t * EMB + j * 64] = nh;
    }
    lds_barrier();
  }
}

// ---------------------------------------------------------------------------
// Fused MLP: 512 WGs x 512 thr (8 waves, LDS-bound 1 WG/CU => 2 waves/SIMD).
// Wave wv owns col-tiles nt = wv*4+ct. Fragment-ordered weights: one
// coalesced 1KB load per (nt,kc,kk). Depth-1 double-buffered wf prefetch +
// per-iter a8 preload; fully unrolled so buffer indices are compile-time.
// ---------------------------------------------------------------------------
template<int KC>
__device__ __forceinline__ void mlp_layer(
    const bf16_t* __restrict__ Wf, const float* __restrict__ bias,
    bf16_t (*act)[520], int wv, int lane, int l15, int quad)
{
  constexpr int NIT = KC * 4;
  f32x4 acc[4][8] = {};
  bf16x8 wf[2][4];

#pragma unroll
  for (int ct = 0; ct < 4; ++ct)
    wf[0][ct] = *reinterpret_cast<const bf16x8*>(
        Wf + (((size_t)(wv * 4 + ct) * KC) << 11) + lane * 8);

#pragma unroll
  for (int it = 0; it < NIT; ++it) {
    const int cur = it & 1, nxt = cur ^ 1;
    if (it + 1 < NIT) {
      const int kc1 = (it + 1) >> 2, kk1 = (it + 1) & 3;
#pragma unroll
      for (int ct = 0; ct < 4; ++ct)
        wf[nxt][ct] = *reinterpret_cast<const bf16x8*>(
            Wf + ((((size_t)(wv * 4 + ct) * KC + kc1) * 4 + kk1) << 9) + lane * 8);
    }
    const int kc = it >> 2, kk = it & 3;
    bf16x8 a8[8];
#pragma unroll
    for (int mt = 0; mt < 8; ++mt)
      a8[mt] = *reinterpret_cast<const bf16x8*>(
          &act[mt * 16 + l15][kc * 128 + kk * 32 + quad * 8]);
#pragma unroll
    for (int mt = 0; mt < 8; ++mt)
#pragma unroll
      for (int ct = 0; ct < 4; ++ct)
        acc[ct][mt] = MFMA16(a8[mt], wf[cur][ct], acc[ct][mt]);
  }

  __syncthreads();
#pragma unroll
  for (int ct = 0; ct < 4; ++ct) {
    const int n = wv * 64 + ct * 16 + l15;
    const float b = bias[n];
#pragma unroll
    for (int mt = 0; mt < 8; ++mt)
#pragma unroll
      for (int r = 0; r < 4; ++r) {
        float x = acc[ct][mt][r] + b;
        x = (x > 0.f) ? x : (__expf(x) - 1.f);   // ELU
        act[mt * 16 + quad * 4 + r][n] = (bf16_t)x;
      }
  }
  __syncthreads();
}

__global__ __launch_bounds__(512, 2) void mlp_kernel(
    const bf16_t* __restrict__ hs,
    const bf16_t* __restrict__ w1, const float* __restrict__ b1,
    const bf16_t* __restrict__ w2, const float* __restrict__ b2,
    const bf16_t* __restrict__ w3, const float* __restrict__ b3,
    const bf16_t* __restrict__ muw, const float* __restrict__ mub,
    float* __restrict__ out)
{
  __shared__ __align__(16) bf16_t act[128][520];

  const int tid  = threadIdx.x;
  const int wv   = tid >> 6;
  const int lane = tid & 63;
  const int l15  = lane & 15;
  const int quad = lane >> 4;
  const size_t r0 = (size_t)blockIdx.x * 128;

  for (int v = tid; v < 128 * 32; v += 512) {
    const int rr = v >> 5, cc = v & 31;
    bf16x8 x = *reinterpret_cast<const bf16x8*>(hs + (r0 + rr) * EMB + cc * 8);
    *reinterpret_cast<bf16x8*>(&act[rr][cc * 8]) = x;
  }
  __syncthreads();

  mlp_layer<2>(w1, b1, act, wv, lane, l15, quad);   // 256 -> 512
  mlp_layer<4>(w2, b2, act, wv, lane, l15, quad);   // 512 -> 512
  mlp_layer<4>(w3, b3, act, wv, lane, l15, quad);   // 512 -> 512

  // mu head: wave wv -> col-tile (wv&3), m-tiles (wv>>2)*4 .. +4
  f32x4 macc[4] = {};
  const int nt  = wv & 3;
  const int n   = nt * 16 + l15;
  const int mtb = (wv >> 2) * 4;
#pragma unroll
  for (int it = 0; it < 16; ++it) {
    const int kc = it >> 2, kk = it & 3;
    bf16x8 wfm = *reinterpret_cast<const bf16x8*>(
        muw + ((((size_t)nt * 4 + kc) * 4 + kk) << 9) + lane * 8);
#pragma unroll
    for (int i = 0; i < 4; ++i) {
      bf16x8 a = *reinterpret_cast<const bf16x8*>(
          &act[(mtb + i) * 16 + l15][kc * 128 + kk * 32 + quad * 8]);
      macc[i] = MFMA16(a, wfm, macc[i]);
    }
  }
  const float mb = mub[n];
#pragma unroll
  for (int i = 0; i < 4; ++i)
#pragma unroll
    for (int r = 0; r < 4; ++r)
      out[(r0 + (mtb + i) * 16 + quad * 4 + r) * OUTD + n] = macc[i][r] + mb;
}

// ---------------------------------------------------------------------------
extern "C" void kernel_launch(void* const* d_in, const int* in_sizes, int n_in,
                              void* d_out, int out_size, void* d_ws, size_t ws_size,
                              hipStream_t stream) {
  char* ws = (char*)d_ws;

  convert_kernel<<<256, 256, 0, stream>>>(
      (const float*)d_in[3], (const float*)d_in[6], (const float*)d_in[8],
      (const float*)d_in[10], (const float*)d_in[12], ws);

  emb_kernel<<<512, 256, 0, stream>>>(
      (const float*)d_in[0], (const float*)d_in[1], (const float*)d_in[2],
      (float*)(ws + H0_OFF));

  gru_kernel<<<128, 256, 0, stream>>>(
      (const float*)(ws + H0_OFF), (const bf16_t*)(ws + WHH_OFF),
      (const float*)d_in[4], (const float*)d_in[5],
      (bf16_t*)(ws + HS_OFF));

  mlp_kernel<<<512, 512, 0, stream>>>(
      (const bf16_t*)(ws + HS_OFF),
      (const bf16_t*)(ws + W1_OFF), (const float*)d_in[7],
      (const bf16_t*)(ws + W2_OFF), (const float*)d_in[9],
      (const bf16_t*)(ws + W3_OFF), (const float*)d_in[11],
      (const bf16_t*)(ws + MUW_OFF), (const float*)d_in[13],
      (float*)d_out);
}

// Round 6
// 346.291 us; speedup vs baseline: 1.1326x; 1.0064x over previous
//
#include <hip/hip_runtime.h>
#include <hip/hip_bf16.h>

// R28: isolation round. R27 failed marginally (absmax 0.0273 vs thr 0.0269)
// despite both changes being math-identical to passing predecessors -> prime
// suspect is inline-asm MFMA hazard fragility under register re-allocation
// (compiler can't see asm internals; R25's s_nop wall was schedule-specific).
// This round: GRU reverted BYTE-IDENTICAL to R25 (known-good, 161us);
// MLP keeps R27's restructure (64-row tiles, 1024 WGs x 256 thr, 66.5KB LDS
// -> 2 WG/CU so one WG's epilogue/barriers overlap the other's MFMA;
// fragment-ordered weights + depth-1 prefetch). Passes -> MLP win banked and
// bug localized to GRU remap. Fails -> MLP is the bug.

typedef __bf16 bf16_t;
typedef __bf16 bf16x2 __attribute__((ext_vector_type(2)));
typedef __bf16 bf16x8 __attribute__((ext_vector_type(8)));
typedef float f32x4 __attribute__((ext_vector_type(4)));

#define MFMA16(a, b, c) __builtin_amdgcn_mfma_f32_16x16x32_bf16(a, b, c, 0, 0, 0)

#define EMB 256
#define TSTEPS 128
#define OUTD 64

#define HS_OFF   0u           // bf16 65536x256 = 33,554,432
#define H0_OFF   33554432u    // f32 512x256   = 524,288
#define WHH_OFF  34078720u    // bf16 768x256  = 393,216
#define W1_OFF   34471936u    // bf16 512x256  = 262,144 (fragment-ordered)
#define W2_OFF   34734080u    // bf16 512x512  = 524,288 (fragment-ordered)
#define W3_OFF   35258368u    // bf16 512x512  = 524,288 (fragment-ordered)
#define MUW_OFF  35782656u    // bf16 64x512   = 65,536  (fragment-ordered)

__device__ __forceinline__ float rcpf(float x){ return __builtin_amdgcn_rcpf(x); }
__device__ __forceinline__ void lds_barrier() {
  asm volatile("s_waitcnt lgkmcnt(0)\n\ts_barrier" ::: "memory");
}

// ---------------------------------------------------------------------------
// Fragment layout: element (n, k) of an NxK weight, with n = nt*16 + l15,
// k = kc*128 + kk*32 + quad*8 + e, lane = quad*16 + l15, lives at
//   Wf[(((nt*KC + kc)*4 + kk) << 9) + lane*8 + e]
// so one wave's (nt,kc,kk) fragment is 1024 contiguous bytes, lane i at 16i.
// ---------------------------------------------------------------------------
template<int KC>
__device__ __forceinline__ void conv_frag(
    const float* __restrict__ src, bf16_t* __restrict__ dst,
    int NK, int g, int G)
{
  const int K = KC * 128;
  for (int i = g; i < NK; i += G) {
    const int e    = i & 7;
    const int lane = (i >> 3) & 63;
    const int kk   = (i >> 9) & 3;
    const int rem  = i >> 11;
    const int kc   = rem & (KC - 1);
    const int nt   = rem / KC;          // KC pow2 -> shift
    const int l15  = lane & 15, quad = lane >> 4;
    dst[i] = (bf16_t)src[(size_t)(nt * 16 + l15) * K + kc * 128 + kk * 32 + quad * 8 + e];
  }
}

__global__ __launch_bounds__(256) void convert_kernel(
    const float* __restrict__ whh, const float* __restrict__ w1,
    const float* __restrict__ w2, const float* __restrict__ w3,
    const float* __restrict__ muw, char* __restrict__ ws)
{
  const int g = blockIdx.x * 256 + threadIdx.x;
  const int G = gridDim.x * 256;
  bf16_t* d;
  d = (bf16_t*)(ws + WHH_OFF); for (int i = g; i < 196608; i += G) d[i] = (bf16_t)whh[i];
  conv_frag<2>(w1,  (bf16_t*)(ws + W1_OFF),  131072, g, G);
  conv_frag<4>(w2,  (bf16_t*)(ws + W2_OFF),  262144, g, G);
  conv_frag<4>(w3,  (bf16_t*)(ws + W3_OFF),  262144, g, G);
  conv_frag<4>(muw, (bf16_t*)(ws + MUW_OFF), 32768,  g, G);
}

// ---------------------------------------------------------------------------
__global__ __launch_bounds__(256) void emb_kernel(
    const float* __restrict__ z_t, const float* __restrict__ z_g,
    const float* __restrict__ w_emb, float* __restrict__ h0)
{
  __shared__ float zrow[128];
  const int bw = blockIdx.x, tid = threadIdx.x;
  if (tid < 128)
    zrow[tid] = (tid < 64) ? z_t[bw * 64 + tid] : z_g[(bw >> 4) * 64 + (tid - 64)];
  __syncthreads();
  const float4* wp = reinterpret_cast<const float4*>(w_emb + (size_t)tid * 128);
  float s = 0.f;
#pragma unroll
  for (int k4 = 0; k4 < 32; ++k4) {
    const float4 w = wp[k4];
    s += zrow[k4 * 4 + 0] * w.x + zrow[k4 * 4 + 1] * w.y
       + zrow[k4 * 4 + 2] * w.z + zrow[k4 * 4 + 3] * w.w;
  }
  h0[(size_t)bw * 256 + tid] = s;
}

// ---------------------------------------------------------------------------
// GRU: BYTE-IDENTICAL to R25 (known-good). 128 WGs x 256 thr (4 waves,
// 1 wave/SIMD, 512-reg unified budget), 4 rows/WG at A-rows {0,4,8,12}.
// ct 0..7 AGPR-pinned (asm "a"), ct 8..11 VGPR intrinsic. Hazard fences
// around the asm MFMA block.
// ---------------------------------------------------------------------------
__global__ __launch_bounds__(256, 1) void gru_kernel(
    const float* __restrict__ h0, const bf16_t* __restrict__ w_hh,
    const float* __restrict__ b_ih, const float* __restrict__ b_hh,
    bf16_t* __restrict__ hs)
{
  __shared__ __align__(16) bf16_t h16[2][16][264];

  const int tid  = threadIdx.x;
  const int wv   = tid >> 6;      // 0..3
  const int lane = tid & 63;
  const int l15  = lane & 15;
  const int quad = lane >> 4;     // 0..3 == batch row within WG
  const int bw0  = blockIdx.x * 4;
  const int c0   = wv * 16 + l15; // 0..63

  // AGPR-pinned: gates r (ct 0..3) and z (ct 4..7) -> 64 frags = 256 AGPRs
  bf16x8 wA[8][8];
#pragma unroll
  for (int ct = 0; ct < 8; ++ct) {
    const int n = (ct >> 2) * 256 + (ct & 3) * 64 + c0;
#pragma unroll
    for (int kk = 0; kk < 8; ++kk)
      wA[ct][kk] = *reinterpret_cast<const bf16x8*>(
          w_hh + (size_t)n * 256 + kk * 32 + quad * 8);
  }
  // VGPR: gate n (cols 512 + j*64 + c0) -> 32 frags = 128 VGPRs
  bf16x8 wV[4][8];
#pragma unroll
  for (int j = 0; j < 4; ++j) {
    const int n = 512 + j * 64 + c0;
#pragma unroll
    for (int kk = 0; kk < 8; ++kk)
      wV[j][kk] = *reinterpret_cast<const bf16x8*>(
          w_hh + (size_t)n * 256 + kk * 32 + quad * 8);
  }

  float br[4], bz[4], bin[4], bhn[4], hm[4];
#pragma unroll
  for (int j = 0; j < 4; ++j) {
    const int c = c0 + j * 64;
    br[j]  = b_ih[c]       + b_hh[c];
    bz[j]  = b_ih[256 + c] + b_hh[256 + c];
    bin[j] = b_ih[512 + c];
    bhn[j] = b_hh[512 + c];
    hm[j]  = h0[(size_t)(bw0 + quad) * 256 + c];
  }

  {
    bf16x8 zv;
#pragma unroll
    for (int e = 0; e < 8; ++e) zv[e] = (bf16_t)0.f;
    for (int i = tid; i < 1056; i += 256)   // 2*16*264/8
      reinterpret_cast<bf16x8*>(h16)[i] = zv;
  }
  __syncthreads();
#pragma unroll
  for (int j = 0; j < 4; ++j)
    h16[0][quad * 4][c0 + j * 64] = (bf16_t)hm[j];
  __syncthreads();

  bf16_t* hsp = hs + ((size_t)(bw0 + quad) * TSTEPS) * EMB + c0;

#pragma unroll 1
  for (int t = 0; t < TSTEPS; ++t) {
    const bf16_t (*hr)[264] = h16[t & 1];
    bf16_t (*hw)[264] = h16[(t & 1) ^ 1];

    bf16x8 a8[8];
#pragma unroll
    for (int kk = 0; kk < 8; ++kk)
      a8[kk] = *reinterpret_cast<const bf16x8*>(&hr[l15][kk * 32 + quad * 8]);

    f32x4 acc[12] = {};
    __builtin_amdgcn_sched_barrier(0);
    asm volatile("s_nop 1" :::);

#pragma unroll
    for (int kk = 0; kk < 8; ++kk) {
#pragma unroll
      for (int ct = 0; ct < 8; ++ct)
        asm("v_mfma_f32_16x16x32_bf16 %0, %1, %2, %0"
            : "+v"(acc[ct]) : "v"(a8[kk]), "a"(wA[ct][kk]));
#pragma unroll
      for (int j = 0; j < 4; ++j)
        acc[8 + j] = MFMA16(a8[kk], wV[j][kk], acc[8 + j]);
    }

    __builtin_amdgcn_sched_barrier(0);
    asm volatile("s_nop 7\n\ts_nop 7\n\ts_nop 1" :::);
    __builtin_amdgcn_sched_barrier(0);

#pragma unroll
    for (int j = 0; j < 4; ++j) {
      const float gr = acc[j][0]     + br[j];
      const float gz = acc[4 + j][0] + bz[j];
      const float gn = acc[8 + j][0] + bhn[j];
      const float rr = rcpf(1.f + __expf(-gr));
      const float zz = rcpf(1.f + __expf(-gz));
      const float pre = bin[j] + rr * gn;
      const float nn = 1.f - 2.f * rcpf(__expf(2.f * pre) + 1.f);
      hm[j] = nn + zz * (hm[j] - nn);
      const bf16_t nh = (bf16_t)hm[j];
      hw[quad * 4][c0 + j * 64] = nh;
      hsp[(size_t)t * EMB + j * 64] = nh;
    }
    lds_barrier();
  }
}

// ---------------------------------------------------------------------------
// Fused MLP: 1024 WGs x 256 thr (4 waves), 64 rows/WG, LDS 66.5KB -> 2 WG/CU.
// Wave wv owns col-tiles nt = wv*8+ct (128 cols) x 4 m-tiles. Depth-1
// double-buffered wf prefetch; fragment-ordered weights.
// ---------------------------------------------------------------------------
template<int KC>
__device__ __forceinline__ void mlp_layer(
    const bf16_t* __restrict__ Wf, const float* __restrict__ bias,
    bf16_t (*act)[520], int wv, int lane, int l15, int quad)
{
  constexpr int NIT = KC * 4;
  f32x4 acc[8][4] = {};
  bf16x8 wf[2][8];

#pragma unroll
  for (int ct = 0; ct < 8; ++ct)
    wf[0][ct] = *reinterpret_cast<const bf16x8*>(
        Wf + (((size_t)(wv * 8 + ct) * KC) << 11) + lane * 8);

#pragma unroll
  for (int it = 0; it < NIT; ++it) {
    const int cur = it & 1, nxt = cur ^ 1;
    if (it + 1 < NIT) {
      const int kc1 = (it + 1) >> 2, kk1 = (it + 1) & 3;
#pragma unroll
      for (int ct = 0; ct < 8; ++ct)
        wf[nxt][ct] = *reinterpret_cast<const bf16x8*>(
            Wf + ((((size_t)(wv * 8 + ct) * KC + kc1) * 4 + kk1) << 9) + lane * 8);
    }
    const int kc = it >> 2, kk = it & 3;
    bf16x8 a8[4];
#pragma unroll
    for (int mt = 0; mt < 4; ++mt)
      a8[mt] = *reinterpret_cast<const bf16x8*>(
          &act[mt * 16 + l15][kc * 128 + kk * 32 + quad * 8]);
#pragma unroll
    for (int mt = 0; mt < 4; ++mt)
#pragma unroll
      for (int ct = 0; ct < 8; ++ct)
        acc[ct][mt] = MFMA16(a8[mt], wf[cur][ct], acc[ct][mt]);
  }

  __syncthreads();
#pragma unroll
  for (int ct = 0; ct < 8; ++ct) {
    const int n = wv * 128 + ct * 16 + l15;
    const float b = bias[n];
#pragma unroll
    for (int mt = 0; mt < 4; ++mt)
#pragma unroll
      for (int r = 0; r < 4; ++r) {
        float x = acc[ct][mt][r] + b;
        x = (x > 0.f) ? x : (__expf(x) - 1.f);   // ELU
        act[mt * 16 + quad * 4 + r][n] = (bf16_t)x;
      }
  }
  __syncthreads();
}

__global__ __launch_bounds__(256, 2) void mlp_kernel(
    const bf16_t* __restrict__ hs,
    const bf16_t* __restrict__ w1, const float* __restrict__ b1,
    const bf16_t* __restrict__ w2, const float* __restrict__ b2,
    const bf16_t* __restrict__ w3, const float* __restrict__ b3,
    const bf16_t* __restrict__ muw, const float* __restrict__ mub,
    float* __restrict__ out)
{
  __shared__ __align__(16) bf16_t act[64][520];

  const int tid  = threadIdx.x;
  const int wv   = tid >> 6;      // 0..3
  const int lane = tid & 63;
  const int l15  = lane & 15;
  const int quad = lane >> 4;
  const size_t r0 = (size_t)blockIdx.x * 64;

  for (int v = tid; v < 64 * 32; v += 256) {
    const int rr = v >> 5, cc = v & 31;
    bf16x8 x = *reinterpret_cast<const bf16x8*>(hs + (r0 + rr) * EMB + cc * 8);
    *reinterpret_cast<bf16x8*>(&act[rr][cc * 8]) = x;
  }
  __syncthreads();

  mlp_layer<2>(w1, b1, act, wv, lane, l15, quad);   // 256 -> 512
  mlp_layer<4>(w2, b2, act, wv, lane, l15, quad);   // 512 -> 512
  mlp_layer<4>(w3, b3, act, wv, lane, l15, quad);   // 512 -> 512

  // mu head: wave wv -> out col-tile wv (OUTD=64 -> 4 tiles), all 4 m-tiles
  f32x4 macc[4] = {};
  const int n = wv * 16 + l15;
#pragma unroll
  for (int it = 0; it < 16; ++it) {
    const int kc = it >> 2, kk = it & 3;
    bf16x8 wfm = *reinterpret_cast<const bf16x8*>(
        muw + ((((size_t)wv * 4 + kc) * 4 + kk) << 9) + lane * 8);
#pragma unroll
    for (int i = 0; i < 4; ++i) {
      bf16x8 a = *reinterpret_cast<const bf16x8*>(
          &act[i * 16 + l15][kc * 128 + kk * 32 + quad * 8]);
      macc[i] = MFMA16(a, wfm, macc[i]);
    }
  }
  const float mb = mub[n];
#pragma unroll
  for (int i = 0; i < 4; ++i)
#pragma unroll
    for (int r = 0; r < 4; ++r)
      out[(r0 + i * 16 + quad * 4 + r) * OUTD + n] = macc[i][r] + mb;
}

// ---------------------------------------------------------------------------
extern "C" void kernel_launch(void* const* d_in, const int* in_sizes, int n_in,
                              void* d_out, int out_size, void* d_ws, size_t ws_size,
                              hipStream_t stream) {
  char* ws = (char*)d_ws;

  convert_kernel<<<256, 256, 0, stream>>>(
      (const float*)d_in[3], (const float*)d_in[6], (const float*)d_in[8],
      (const float*)d_in[10], (const float*)d_in[12], ws);

  emb_kernel<<<512, 256, 0, stream>>>(
      (const float*)d_in[0], (const float*)d_in[1], (const float*)d_in[2],
      (float*)(ws + H0_OFF));

  gru_kernel<<<128, 256, 0, stream>>>(
      (const float*)(ws + H0_OFF), (const bf16_t*)(ws + WHH_OFF),
      (const float*)d_in[4], (const float*)d_in[5],
      (bf16_t*)(ws + HS_OFF));

  mlp_kernel<<<1024, 256, 0, stream>>>(
      (const bf16_t*)(ws + HS_OFF),
      (const bf16_t*)(ws + W1_OFF), (const float*)d_in[7],
      (const bf16_t*)(ws + W2_OFF), (const float*)d_in[9],
      (const bf16_t*)(ws + W3_OFF), (const float*)d_in[11],
      (const bf16_t*)(ws + MUW_OFF), (const float*)d_in[13],
      (float*)d_out);
}

// Round 7
// 334.334 us; speedup vs baseline: 1.1731x; 1.0358x over previous
//
#include <hip/hip_runtime.h>
#include <hip/hip_bf16.h>

// R29: cut GRU per-step cycles (the ONLY thing that matters: 128 serial steps;
// R27's occupancy idea was structurally wrong). Measured 3020 cyc/step vs
// 1862 MFMA-pipe floor; the gap is ds/gate/barrier latency exposed at
// 1 wave/SIMD. Now 8 waves x 6 tiles (512 thr, 2 waves/SIMD): same per-SIMD
// MFMA work, co-resident wave hides the rest. wfrag 192 VGPR + acc 24 AGPR
// fits 256/wave -> NO inline asm, compiler-managed hazards.
// MLP: operand-swapped MFMA (D row<->n, col<->m) so the epilogue writes one
// ds_write_b64 per (ct,mt) instead of 4 scalar b16 (128->32 writes/layer);
// mu head emits float4 global stores.

typedef __bf16 bf16_t;
typedef __bf16 bf16x2 __attribute__((ext_vector_type(2)));
typedef __bf16 bf16x4 __attribute__((ext_vector_type(4)));
typedef __bf16 bf16x8 __attribute__((ext_vector_type(8)));
typedef float f32x4 __attribute__((ext_vector_type(4)));

#define MFMA16(a, b, c) __builtin_amdgcn_mfma_f32_16x16x32_bf16(a, b, c, 0, 0, 0)

#define EMB 256
#define TSTEPS 128
#define OUTD 64

#define HS_OFF   0u           // bf16 65536x256 = 33,554,432
#define H0_OFF   33554432u    // f32 512x256   = 524,288
#define WHH_OFF  34078720u    // bf16 768x256  = 393,216
#define W1_OFF   34471936u    // bf16 512x256  = 262,144 (fragment-ordered)
#define W2_OFF   34734080u    // bf16 512x512  = 524,288 (fragment-ordered)
#define W3_OFF   35258368u    // bf16 512x512  = 524,288 (fragment-ordered)
#define MUW_OFF  35782656u    // bf16 64x512   = 65,536  (fragment-ordered)

__device__ __forceinline__ float rcpf(float x){ return __builtin_amdgcn_rcpf(x); }
__device__ __forceinline__ void lds_barrier() {
  asm volatile("s_waitcnt lgkmcnt(0)\n\ts_barrier" ::: "memory");
}
__device__ __forceinline__ float eluf(float x) {
  return (x > 0.f) ? x : (__expf(x) - 1.f);
}

// ---------------------------------------------------------------------------
// Fragment layout: element (n, k) of an NxK weight, with n = nt*16 + l15,
// k = kc*128 + kk*32 + quad*8 + e, lane = quad*16 + l15, lives at
//   Wf[(((nt*KC + kc)*4 + kk) << 9) + lane*8 + e]
// ---------------------------------------------------------------------------
template<int KC>
__device__ __forceinline__ void conv_frag(
    const float* __restrict__ src, bf16_t* __restrict__ dst,
    int NK, int g, int G)
{
  const int K = KC * 128;
  for (int i = g; i < NK; i += G) {
    const int e    = i & 7;
    const int lane = (i >> 3) & 63;
    const int kk   = (i >> 9) & 3;
    const int rem  = i >> 11;
    const int kc   = rem & (KC - 1);
    const int nt   = rem / KC;
    const int l15  = lane & 15, quad = lane >> 4;
    dst[i] = (bf16_t)src[(size_t)(nt * 16 + l15) * K + kc * 128 + kk * 32 + quad * 8 + e];
  }
}

__global__ __launch_bounds__(256) void convert_kernel(
    const float* __restrict__ whh, const float* __restrict__ w1,
    const float* __restrict__ w2, const float* __restrict__ w3,
    const float* __restrict__ muw, char* __restrict__ ws)
{
  const int g = blockIdx.x * 256 + threadIdx.x;
  const int G = gridDim.x * 256;
  bf16_t* d;
  d = (bf16_t*)(ws + WHH_OFF); for (int i = g; i < 196608; i += G) d[i] = (bf16_t)whh[i];
  conv_frag<2>(w1,  (bf16_t*)(ws + W1_OFF),  131072, g, G);
  conv_frag<4>(w2,  (bf16_t*)(ws + W2_OFF),  262144, g, G);
  conv_frag<4>(w3,  (bf16_t*)(ws + W3_OFF),  262144, g, G);
  conv_frag<4>(muw, (bf16_t*)(ws + MUW_OFF), 32768,  g, G);
}

// ---------------------------------------------------------------------------
__global__ __launch_bounds__(256) void emb_kernel(
    const float* __restrict__ z_t, const float* __restrict__ z_g,
    const float* __restrict__ w_emb, float* __restrict__ h0)
{
  __shared__ float zrow[128];
  const int bw = blockIdx.x, tid = threadIdx.x;
  if (tid < 128)
    zrow[tid] = (tid < 64) ? z_t[bw * 64 + tid] : z_g[(bw >> 4) * 64 + (tid - 64)];
  __syncthreads();
  const float4* wp = reinterpret_cast<const float4*>(w_emb + (size_t)tid * 128);
  float s = 0.f;
#pragma unroll
  for (int k4 = 0; k4 < 32; ++k4) {
    const float4 w = wp[k4];
    s += zrow[k4 * 4 + 0] * w.x + zrow[k4 * 4 + 1] * w.y
       + zrow[k4 * 4 + 2] * w.z + zrow[k4 * 4 + 3] * w.w;
  }
  h0[(size_t)bw * 256 + tid] = s;
}

// ---------------------------------------------------------------------------
// GRU: 128 WGs x 512 thr (8 waves, 2 waves/SIMD => 256 regs/wave).
// 4 rows/WG at A-rows {0,4,8,12} -> C row m=4*quad is reg 0 of every lane.
// Wave wv (0..7) owns gate cols c(s) = wv*32 + s*16 + l15, s=0,1, within each
// gate group g (r,z,n): tile ct = g*2+s at n = g*256 + wv*32 + s*16.
// wfrag 6x8 = 192 VGPR (fits -> plain intrinsics, no asm), acc 24 -> AGPR.
// Per-SIMD MFMA/step unchanged (2 waves x 48 = 96 = 1862 cyc); the second
// wave hides ds_read latency + gate VALU + barrier skew.
// ---------------------------------------------------------------------------
__global__ __launch_bounds__(512, 2) void gru_kernel(
    const float* __restrict__ h0, const bf16_t* __restrict__ w_hh,
    const float* __restrict__ b_ih, const float* __restrict__ b_hh,
    bf16_t* __restrict__ hs)
{
  __shared__ __align__(16) bf16_t h16[2][16][264];

  const int tid  = threadIdx.x;
  const int wv   = tid >> 6;      // 0..7
  const int lane = tid & 63;
  const int l15  = lane & 15;
  const int quad = lane >> 4;     // 0..3 == batch row within WG
  const int bw0  = blockIdx.x * 4;
  const int cA   = wv * 32 + l15; // col for s=0 (s=1 is cA+16)

  // register-resident W_hh: 6 tiles/wave (ct = g*2+s), 8 k-frags each
  bf16x8 wf[6][8];
#pragma unroll
  for (int g = 0; g < 3; ++g)
#pragma unroll
    for (int s = 0; s < 2; ++s) {
      const int n = g * 256 + cA + s * 16;
#pragma unroll
      for (int kk = 0; kk < 8; ++kk)
        wf[g * 2 + s][kk] = *reinterpret_cast<const bf16x8*>(
            w_hh + (size_t)n * 256 + kk * 32 + quad * 8);
    }

  // per-thread gate state: row = quad, cols cA + s*16 (s=0,1)
  float br[2], bz[2], bin[2], bhn[2], hm[2];
#pragma unroll
  for (int s = 0; s < 2; ++s) {
    const int c = cA + s * 16;
    br[s]  = b_ih[c]       + b_hh[c];
    bz[s]  = b_ih[256 + c] + b_hh[256 + c];
    bin[s] = b_ih[512 + c];
    bhn[s] = b_hh[512 + c];
    hm[s]  = h0[(size_t)(bw0 + quad) * 256 + c];
  }

  // zero both buffers (padding rows must read as 0), then seed buf 0
  {
    bf16x8 zv;
#pragma unroll
    for (int e = 0; e < 8; ++e) zv[e] = (bf16_t)0.f;
    for (int i = tid; i < 1056; i += 512)   // 2*16*264/8
      reinterpret_cast<bf16x8*>(h16)[i] = zv;
  }
  __syncthreads();
#pragma unroll
  for (int s = 0; s < 2; ++s)
    h16[0][quad * 4][cA + s * 16] = (bf16_t)hm[s];
  __syncthreads();

  bf16_t* hsp = hs + ((size_t)(bw0 + quad) * TSTEPS) * EMB + cA;

#pragma unroll 1
  for (int t = 0; t < TSTEPS; ++t) {
    const bf16_t (*hr)[264] = h16[t & 1];
    bf16_t (*hw)[264] = h16[(t & 1) ^ 1];

    f32x4 acc[6] = {};
#pragma unroll
    for (int kk = 0; kk < 8; ++kk) {
      const bf16x8 a = *reinterpret_cast<const bf16x8*>(&hr[l15][kk * 32 + quad * 8]);
#pragma unroll
      for (int ct = 0; ct < 6; ++ct)
        acc[ct] = MFMA16(a, wf[ct][kk], acc[ct]);
    }

    // gates fully in-register: reg 0 of each acc is the real row (m=4*quad)
#pragma unroll
    for (int s = 0; s < 2; ++s) {
      const float gr = acc[s][0]     + br[s];
      const float gz = acc[2 + s][0] + bz[s];
      const float gn = acc[4 + s][0] + bhn[s];
      const float rr = rcpf(1.f + __expf(-gr));
      const float zz = rcpf(1.f + __expf(-gz));
      const float pre = bin[s] + rr * gn;
      const float nn = 1.f - 2.f * rcpf(__expf(2.f * pre) + 1.f);
      hm[s] = nn + zz * (hm[s] - nn);
      const bf16_t nh = (bf16_t)hm[s];
      hw[quad * 4][cA + s * 16] = nh;
      hsp[(size_t)t * EMB + s * 16] = nh;
    }
    lds_barrier();   // hw writes drained; next step reads hw as hr
  }
}

// ---------------------------------------------------------------------------
// Fused MLP: 1024 WGs x 256 thr (4 waves), 64 rows/WG, 66.5KB LDS -> 2 WG/CU.
// Operand-swapped MFMA: D col = m (l15), D row = n (quad*4+r) -> thread holds
// 4-elem ROW segments -> one ds_write_b64 per (ct,mt) in the epilogue.
// ---------------------------------------------------------------------------
template<int KC>
__device__ __forceinline__ void mlp_layer(
    const bf16_t* __restrict__ Wf, const float* __restrict__ bias,
    bf16_t (*act)[520], int wv, int lane, int l15, int quad)
{
  constexpr int NIT = KC * 4;
  f32x4 acc[8][4] = {};
  bf16x8 wf[2][8];

#pragma unroll
  for (int ct = 0; ct < 8; ++ct)
    wf[0][ct] = *reinterpret_cast<const bf16x8*>(
        Wf + (((size_t)(wv * 8 + ct) * KC) << 11) + lane * 8);

#pragma unroll
  for (int it = 0; it < NIT; ++it) {
    const int cur = it & 1, nxt = cur ^ 1;
    if (it + 1 < NIT) {
      const int kc1 = (it + 1) >> 2, kk1 = (it + 1) & 3;
#pragma unroll
      for (int ct = 0; ct < 8; ++ct)
        wf[nxt][ct] = *reinterpret_cast<const bf16x8*>(
            Wf + ((((size_t)(wv * 8 + ct) * KC + kc1) * 4 + kk1) << 9) + lane * 8);
    }
    const int kc = it >> 2, kk = it & 3;
    bf16x8 a8[4];
#pragma unroll
    for (int mt = 0; mt < 4; ++mt)
      a8[mt] = *reinterpret_cast<const bf16x8*>(
          &act[mt * 16 + l15][kc * 128 + kk * 32 + quad * 8]);
#pragma unroll
    for (int mt = 0; mt < 4; ++mt)
#pragma unroll
      for (int ct = 0; ct < 8; ++ct)
        acc[ct][mt] = MFMA16(wf[cur][ct], a8[mt], acc[ct][mt]);  // swapped
  }

  __syncthreads();
#pragma unroll
  for (int ct = 0; ct < 8; ++ct) {
    const int nb = (wv * 8 + ct) * 16 + quad * 4;   // 4-aligned col base
    const float4 b4 = *reinterpret_cast<const float4*>(bias + nb);
#pragma unroll
    for (int mt = 0; mt < 4; ++mt) {
      bf16x4 v;
      v[0] = (bf16_t)eluf(acc[ct][mt][0] + b4.x);
      v[1] = (bf16_t)eluf(acc[ct][mt][1] + b4.y);
      v[2] = (bf16_t)eluf(acc[ct][mt][2] + b4.z);
      v[3] = (bf16_t)eluf(acc[ct][mt][3] + b4.w);
      *reinterpret_cast<bf16x4*>(&act[mt * 16 + l15][nb]) = v;
    }
  }
  __syncthreads();
}

__global__ __launch_bounds__(256, 2) void mlp_kernel(
    const bf16_t* __restrict__ hs,
    const bf16_t* __restrict__ w1, const float* __restrict__ b1,
    const bf16_t* __restrict__ w2, const float* __restrict__ b2,
    const bf16_t* __restrict__ w3, const float* __restrict__ b3,
    const bf16_t* __restrict__ muw, const float* __restrict__ mub,
    float* __restrict__ out)
{
  __shared__ __align__(16) bf16_t act[64][520];

  const int tid  = threadIdx.x;
  const int wv   = tid >> 6;      // 0..3
  const int lane = tid & 63;
  const int l15  = lane & 15;
  const int quad = lane >> 4;
  const size_t r0 = (size_t)blockIdx.x * 64;

  for (int v = tid; v < 64 * 32; v += 256) {
    const int rr = v >> 5, cc = v & 31;
    bf16x8 x = *reinterpret_cast<const bf16x8*>(hs + (r0 + rr) * EMB + cc * 8);
    *reinterpret_cast<bf16x8*>(&act[rr][cc * 8]) = x;
  }
  __syncthreads();

  mlp_layer<2>(w1, b1, act, wv, lane, l15, quad);   // 256 -> 512
  mlp_layer<4>(w2, b2, act, wv, lane, l15, quad);   // 512 -> 512
  mlp_layer<4>(w3, b3, act, wv, lane, l15, quad);   // 512 -> 512

  // mu head (swapped): wave wv -> out col-tile wv; D row = n = quad*4+r,
  // D col = m = l15 -> float4 stores at out[row][wv*16+quad*4 ..+4].
  f32x4 macc[4] = {};
#pragma unroll
  for (int it = 0; it < 16; ++it) {
    const int kc = it >> 2, kk = it & 3;
    bf16x8 wfm = *reinterpret_cast<const bf16x8*>(
        muw + ((((size_t)wv * 4 + kc) * 4 + kk) << 9) + lane * 8);
#pragma unroll
    for (int i = 0; i < 4; ++i) {
      bf16x8 a = *reinterpret_cast<const bf16x8*>(
          &act[i * 16 + l15][kc * 128 + kk * 32 + quad * 8]);
      macc[i] = MFMA16(wfm, a, macc[i]);
    }
  }
  const int nb = wv * 16 + quad * 4;
  const float4 mb4 = *reinterpret_cast<const float4*>(mub + nb);
#pragma unroll
  for (int i = 0; i < 4; ++i) {
    float4 o;
    o.x = macc[i][0] + mb4.x;
    o.y = macc[i][1] + mb4.y;
    o.z = macc[i][2] + mb4.z;
    o.w = macc[i][3] + mb4.w;
    *reinterpret_cast<float4*>(out + (r0 + i * 16 + l15) * OUTD + nb) = o;
  }
}

// ---------------------------------------------------------------------------
extern "C" void kernel_launch(void* const* d_in, const int* in_sizes, int n_in,
                              void* d_out, int out_size, void* d_ws, size_t ws_size,
                              hipStream_t stream) {
  char* ws = (char*)d_ws;

  convert_kernel<<<256, 256, 0, stream>>>(
      (const float*)d_in[3], (const float*)d_in[6], (const float*)d_in[8],
      (const float*)d_in[10], (const float*)d_in[12], ws);

  emb_kernel<<<512, 256, 0, stream>>>(
      (const float*)d_in[0], (const float*)d_in[1], (const float*)d_in[2],
      (float*)(ws + H0_OFF));

  gru_kernel<<<128, 512, 0, stream>>>(
      (const float*)(ws + H0_OFF), (const bf16_t*)(ws + WHH_OFF),
      (const float*)d_in[4], (const float*)d_in[5],
      (bf16_t*)(ws + HS_OFF));

  mlp_kernel<<<1024, 256, 0, stream>>>(
      (const bf16_t*)(ws + HS_OFF),
      (const bf16_t*)(ws + W1_OFF), (const float*)d_in[7],
      (const bf16_t*)(ws + W2_OFF), (const float*)d_in[9],
      (const bf16_t*)(ws + W3_OFF), (const float*)d_in[11],
      (const bf16_t*)(ws + MUW_OFF), (const float*)d_in[13],
      (float*)d_out);
}

// Round 8
// 322.744 us; speedup vs baseline: 1.2152x; 1.0359x over previous
//
#include <hip/hip_runtime.h>
#include <hip/hip_bf16.h>

// R30: four targeted fixes from R29 ledger analysis.
// (1) mu head reverted to R28 coalesced scalar-store form: R29's swapped mu
//     stored float4 at row-strided per-lane addrs -> 4x write amplification
//     (WRITE_SIZE 71MB vs 16.8MB output). Layer epilogues stay swapped (good).
// (2) GRU h16 stride 264->272 elems: 132dw%32=4 made ds_read_b128 an 8-way
//     bank conflict (4.19M cycles); 136dw%32=8 spreads to 16 banks (4-way).
// (3) convert+emb fused into one kernel: probes the ~55us fixed non-dispatch
//     overhead (graph node cost) identified by subtractive timing.
// (4) convert vectorized 8-wide (2xfloat4 -> bf16x8, coalesced both sides).
// GRU otherwise byte-identical to R29 (intrinsic-only, wfrag in AGPRs).

typedef __bf16 bf16_t;
typedef __bf16 bf16x2 __attribute__((ext_vector_type(2)));
typedef __bf16 bf16x4 __attribute__((ext_vector_type(4)));
typedef __bf16 bf16x8 __attribute__((ext_vector_type(8)));
typedef float f32x4 __attribute__((ext_vector_type(4)));

#define MFMA16(a, b, c) __builtin_amdgcn_mfma_f32_16x16x32_bf16(a, b, c, 0, 0, 0)

#define EMB 256
#define TSTEPS 128
#define OUTD 64

#define HS_OFF   0u           // bf16 65536x256 = 33,554,432
#define H0_OFF   33554432u    // f32 512x256   = 524,288
#define WHH_OFF  34078720u    // bf16 768x256  = 393,216
#define W1_OFF   34471936u    // bf16 512x256  = 262,144 (fragment-ordered)
#define W2_OFF   34734080u    // bf16 512x512  = 524,288 (fragment-ordered)
#define W3_OFF   35258368u    // bf16 512x512  = 524,288 (fragment-ordered)
#define MUW_OFF  35782656u    // bf16 64x512   = 65,536  (fragment-ordered)

__device__ __forceinline__ float rcpf(float x){ return __builtin_amdgcn_rcpf(x); }
__device__ __forceinline__ void lds_barrier() {
  asm volatile("s_waitcnt lgkmcnt(0)\n\ts_barrier" ::: "memory");
}
__device__ __forceinline__ float eluf(float x) {
  return (x > 0.f) ? x : (__expf(x) - 1.f);
}
__device__ __forceinline__ bf16x8 cvt8(const float* __restrict__ s) {
  const float4 a = *reinterpret_cast<const float4*>(s);
  const float4 b = *reinterpret_cast<const float4*>(s + 4);
  bf16x8 v;
  v[0] = (bf16_t)a.x; v[1] = (bf16_t)a.y; v[2] = (bf16_t)a.z; v[3] = (bf16_t)a.w;
  v[4] = (bf16_t)b.x; v[5] = (bf16_t)b.y; v[6] = (bf16_t)b.z; v[7] = (bf16_t)b.w;
  return v;
}

// ---------------------------------------------------------------------------
// Fragment layout: element (n, k) of an NxK weight, n = nt*16 + l15,
// k = kc*128 + kk*32 + quad*8 + e, lane = quad*16 + l15, lives at
//   Wf[(((nt*KC + kc)*4 + kk) << 9) + lane*8 + e]
// Vectorized converter: one thread-iter moves 8 consecutive dst elems
// (= 8 consecutive src floats), i8 indexes 8-elem chunks.
// ---------------------------------------------------------------------------
template<int KC, int LOGKC>
__device__ __forceinline__ void conv_frag8(
    const float* __restrict__ src, bf16_t* __restrict__ dst,
    int NK8, int g, int G)
{
  const int K = KC * 128;
  for (int i8 = g; i8 < NK8; i8 += G) {
    const int l15  = i8 & 15;
    const int quad = (i8 >> 4) & 3;
    const int kk   = (i8 >> 6) & 3;
    const int rem  = i8 >> 8;
    const int kc   = rem & (KC - 1);
    const int nt   = rem >> LOGKC;
    *reinterpret_cast<bf16x8*>(dst + (size_t)i8 * 8) =
        cvt8(src + (size_t)(nt * 16 + l15) * K + kc * 128 + kk * 32 + quad * 8);
  }
}

// Fused convert + embedding: blocks 0..511 do emb rows, 512..767 do convert.
__global__ __launch_bounds__(256) void ce_kernel(
    const float* __restrict__ z_t, const float* __restrict__ z_g,
    const float* __restrict__ w_emb, float* __restrict__ h0,
    const float* __restrict__ whh, const float* __restrict__ w1,
    const float* __restrict__ w2, const float* __restrict__ w3,
    const float* __restrict__ muw, char* __restrict__ ws)
{
  const int tid = threadIdx.x;
  if (blockIdx.x < 512) {
    // ---- embedding: one bw row per WG ----
    __shared__ float zrow[128];
    const int bw = blockIdx.x;
    if (tid < 128)
      zrow[tid] = (tid < 64) ? z_t[bw * 64 + tid] : z_g[(bw >> 4) * 64 + (tid - 64)];
    __syncthreads();
    const float4* wp = reinterpret_cast<const float4*>(w_emb + (size_t)tid * 128);
    float s = 0.f;
#pragma unroll
    for (int k4 = 0; k4 < 32; ++k4) {
      const float4 w = wp[k4];
      s += zrow[k4 * 4 + 0] * w.x + zrow[k4 * 4 + 1] * w.y
         + zrow[k4 * 4 + 2] * w.z + zrow[k4 * 4 + 3] * w.w;
    }
    h0[(size_t)bw * 256 + tid] = s;
  } else {
    // ---- weight conversion (8-wide, coalesced) ----
    const int g = (blockIdx.x - 512) * 256 + tid;
    const int G = 256 * 256;
    bf16_t* d = (bf16_t*)(ws + WHH_OFF);
    for (int i8 = g; i8 < 24576; i8 += G)      // whh linear copy
      *reinterpret_cast<bf16x8*>(d + (size_t)i8 * 8) = cvt8(whh + (size_t)i8 * 8);
    conv_frag8<2, 1>(w1,  (bf16_t*)(ws + W1_OFF),  16384, g, G);
    conv_frag8<4, 2>(w2,  (bf16_t*)(ws + W2_OFF),  32768, g, G);
    conv_frag8<4, 2>(w3,  (bf16_t*)(ws + W3_OFF),  32768, g, G);
    conv_frag8<4, 2>(muw, (bf16_t*)(ws + MUW_OFF),  4096, g, G);
  }
}

// ---------------------------------------------------------------------------
// GRU: 128 WGs x 512 thr (8 waves, 2 waves/SIMD). 4 rows/WG at A-rows
// {0,4,8,12}. Wave wv owns gate cols cA = wv*32 + l15 (+16 for s=1) in each
// gate group. wfrag 6x8 (AGPR-resident via compiler), acc 24. h16 row stride
// 272 elems (136dw%32=8 -> 16-bank / 4-way on ds_read_b128, was 8-way).
// ---------------------------------------------------------------------------
__global__ __launch_bounds__(512, 2) void gru_kernel(
    const float* __restrict__ h0, const bf16_t* __restrict__ w_hh,
    const float* __restrict__ b_ih, const float* __restrict__ b_hh,
    bf16_t* __restrict__ hs)
{
  __shared__ __align__(16) bf16_t h16[2][16][272];

  const int tid  = threadIdx.x;
  const int wv   = tid >> 6;      // 0..7
  const int lane = tid & 63;
  const int l15  = lane & 15;
  const int quad = lane >> 4;     // 0..3 == batch row within WG
  const int bw0  = blockIdx.x * 4;
  const int cA   = wv * 32 + l15; // col for s=0 (s=1 is cA+16)

  // register-resident W_hh: 6 tiles/wave (ct = g*2+s), 8 k-frags each
  bf16x8 wf[6][8];
#pragma unroll
  for (int g = 0; g < 3; ++g)
#pragma unroll
    for (int s = 0; s < 2; ++s) {
      const int n = g * 256 + cA + s * 16;
#pragma unroll
      for (int kk = 0; kk < 8; ++kk)
        wf[g * 2 + s][kk] = *reinterpret_cast<const bf16x8*>(
            w_hh + (size_t)n * 256 + kk * 32 + quad * 8);
    }

  // per-thread gate state: row = quad, cols cA + s*16 (s=0,1)
  float br[2], bz[2], bin[2], bhn[2], hm[2];
#pragma unroll
  for (int s = 0; s < 2; ++s) {
    const int c = cA + s * 16;
    br[s]  = b_ih[c]       + b_hh[c];
    bz[s]  = b_ih[256 + c] + b_hh[256 + c];
    bin[s] = b_ih[512 + c];
    bhn[s] = b_hh[512 + c];
    hm[s]  = h0[(size_t)(bw0 + quad) * 256 + c];
  }

  // zero both buffers (padding rows must read as 0), then seed buf 0
  {
    bf16x8 zv;
#pragma unroll
    for (int e = 0; e < 8; ++e) zv[e] = (bf16_t)0.f;
    for (int i = tid; i < 1088; i += 512)   // 2*16*272/8
      reinterpret_cast<bf16x8*>(h16)[i] = zv;
  }
  __syncthreads();
#pragma unroll
  for (int s = 0; s < 2; ++s)
    h16[0][quad * 4][cA + s * 16] = (bf16_t)hm[s];
  __syncthreads();

  bf16_t* hsp = hs + ((size_t)(bw0 + quad) * TSTEPS) * EMB + cA;

#pragma unroll 1
  for (int t = 0; t < TSTEPS; ++t) {
    const bf16_t (*hr)[272] = h16[t & 1];
    bf16_t (*hw)[272] = h16[(t & 1) ^ 1];

    f32x4 acc[6] = {};
#pragma unroll
    for (int kk = 0; kk < 8; ++kk) {
      const bf16x8 a = *reinterpret_cast<const bf16x8*>(&hr[l15][kk * 32 + quad * 8]);
#pragma unroll
      for (int ct = 0; ct < 6; ++ct)
        acc[ct] = MFMA16(a, wf[ct][kk], acc[ct]);
    }

    // gates fully in-register: reg 0 of each acc is the real row (m=4*quad)
#pragma unroll
    for (int s = 0; s < 2; ++s) {
      const float gr = acc[s][0]     + br[s];
      const float gz = acc[2 + s][0] + bz[s];
      const float gn = acc[4 + s][0] + bhn[s];
      const float rr = rcpf(1.f + __expf(-gr));
      const float zz = rcpf(1.f + __expf(-gz));
      const float pre = bin[s] + rr * gn;
      const float nn = 1.f - 2.f * rcpf(__expf(2.f * pre) + 1.f);
      hm[s] = nn + zz * (hm[s] - nn);
      const bf16_t nh = (bf16_t)hm[s];
      hw[quad * 4][cA + s * 16] = nh;
      hsp[(size_t)t * EMB + s * 16] = nh;
    }
    lds_barrier();   // hw writes drained; next step reads hw as hr
  }
}

// ---------------------------------------------------------------------------
// Fused MLP: 1024 WGs x 256 thr (4 waves), 64 rows/WG, 66.5KB LDS -> 2 WG/CU.
// Layers: operand-swapped MFMA -> epilogue writes one ds_write_b64 per
// (ct,mt). Mu head: UNSWAPPED (R28 form) -> coalesced scalar global stores.
// ---------------------------------------------------------------------------
template<int KC>
__device__ __forceinline__ void mlp_layer(
    const bf16_t* __restrict__ Wf, const float* __restrict__ bias,
    bf16_t (*act)[520], int wv, int lane, int l15, int quad)
{
  constexpr int NIT = KC * 4;
  f32x4 acc[8][4] = {};
  bf16x8 wf[2][8];

#pragma unroll
  for (int ct = 0; ct < 8; ++ct)
    wf[0][ct] = *reinterpret_cast<const bf16x8*>(
        Wf + (((size_t)(wv * 8 + ct) * KC) << 11) + lane * 8);

#pragma unroll
  for (int it = 0; it < NIT; ++it) {
    const int cur = it & 1, nxt = cur ^ 1;
    if (it + 1 < NIT) {
      const int kc1 = (it + 1) >> 2, kk1 = (it + 1) & 3;
#pragma unroll
      for (int ct = 0; ct < 8; ++ct)
        wf[nxt][ct] = *reinterpret_cast<const bf16x8*>(
            Wf + ((((size_t)(wv * 8 + ct) * KC + kc1) * 4 + kk1) << 9) + lane * 8);
    }
    const int kc = it >> 2, kk = it & 3;
    bf16x8 a8[4];
#pragma unroll
    for (int mt = 0; mt < 4; ++mt)
      a8[mt] = *reinterpret_cast<const bf16x8*>(
          &act[mt * 16 + l15][kc * 128 + kk * 32 + quad * 8]);
#pragma unroll
    for (int mt = 0; mt < 4; ++mt)
#pragma unroll
      for (int ct = 0; ct < 8; ++ct)
        acc[ct][mt] = MFMA16(wf[cur][ct], a8[mt], acc[ct][mt]);  // swapped
  }

  __syncthreads();
#pragma unroll
  for (int ct = 0; ct < 8; ++ct) {
    const int nb = (wv * 8 + ct) * 16 + quad * 4;   // 4-aligned col base
    const float4 b4 = *reinterpret_cast<const float4*>(bias + nb);
#pragma unroll
    for (int mt = 0; mt < 4; ++mt) {
      bf16x4 v;
      v[0] = (bf16_t)eluf(acc[ct][mt][0] + b4.x);
      v[1] = (bf16_t)eluf(acc[ct][mt][1] + b4.y);
      v[2] = (bf16_t)eluf(acc[ct][mt][2] + b4.z);
      v[3] = (bf16_t)eluf(acc[ct][mt][3] + b4.w);
      *reinterpret_cast<bf16x4*>(&act[mt * 16 + l15][nb]) = v;
    }
  }
  __syncthreads();
}

__global__ __launch_bounds__(256, 2) void mlp_kernel(
    const bf16_t* __restrict__ hs,
    const bf16_t* __restrict__ w1, const float* __restrict__ b1,
    const bf16_t* __restrict__ w2, const float* __restrict__ b2,
    const bf16_t* __restrict__ w3, const float* __restrict__ b3,
    const bf16_t* __restrict__ muw, const float* __restrict__ mub,
    float* __restrict__ out)
{
  __shared__ __align__(16) bf16_t act[64][520];

  const int tid  = threadIdx.x;
  const int wv   = tid >> 6;      // 0..3
  const int lane = tid & 63;
  const int l15  = lane & 15;
  const int quad = lane >> 4;
  const size_t r0 = (size_t)blockIdx.x * 64;

  for (int v = tid; v < 64 * 32; v += 256) {
    const int rr = v >> 5, cc = v & 31;
    bf16x8 x = *reinterpret_cast<const bf16x8*>(hs + (r0 + rr) * EMB + cc * 8);
    *reinterpret_cast<bf16x8*>(&act[rr][cc * 8]) = x;
  }
  __syncthreads();

  mlp_layer<2>(w1, b1, act, wv, lane, l15, quad);   // 256 -> 512
  mlp_layer<4>(w2, b2, act, wv, lane, l15, quad);   // 512 -> 512
  mlp_layer<4>(w3, b3, act, wv, lane, l15, quad);   // 512 -> 512

  // mu head (R28 unswapped form): wave wv -> out col-tile wv, all 4 m-tiles.
  // n = wv*16 + l15 -> 16 lanes per quad store 64 contiguous bytes.
  f32x4 macc[4] = {};
  const int n = wv * 16 + l15;
#pragma unroll
  for (int it = 0; it < 16; ++it) {
    const int kc = it >> 2, kk = it & 3;
    bf16x8 wfm = *reinterpret_cast<const bf16x8*>(
        muw + ((((size_t)wv * 4 + kc) * 4 + kk) << 9) + lane * 8);
#pragma unroll
    for (int i = 0; i < 4; ++i) {
      bf16x8 a = *reinterpret_cast<const bf16x8*>(
          &act[i * 16 + l15][kc * 128 + kk * 32 + quad * 8]);
      macc[i] = MFMA16(a, wfm, macc[i]);
    }
  }
  const float mb = mub[n];
#pragma unroll
  for (int i = 0; i < 4; ++i)
#pragma unroll
    for (int r = 0; r < 4; ++r)
      out[(r0 + i * 16 + quad * 4 + r) * OUTD + n] = macc[i][r] + mb;
}

// ---------------------------------------------------------------------------
extern "C" void kernel_launch(void* const* d_in, const int* in_sizes, int n_in,
                              void* d_out, int out_size, void* d_ws, size_t ws_size,
                              hipStream_t stream) {
  char* ws = (char*)d_ws;

  ce_kernel<<<768, 256, 0, stream>>>(
      (const float*)d_in[0], (const float*)d_in[1], (const float*)d_in[2],
      (float*)(ws + H0_OFF),
      (const float*)d_in[3], (const float*)d_in[6], (const float*)d_in[8],
      (const float*)d_in[10], (const float*)d_in[12], ws);

  gru_kernel<<<128, 512, 0, stream>>>(
      (const float*)(ws + H0_OFF), (const bf16_t*)(ws + WHH_OFF),
      (const float*)d_in[4], (const float*)d_in[5],
      (bf16_t*)(ws + HS_OFF));

  mlp_kernel<<<1024, 256, 0, stream>>>(
      (const bf16_t*)(ws + HS_OFF),
      (const bf16_t*)(ws + W1_OFF), (const float*)d_in[7],
      (const bf16_t*)(ws + W2_OFF), (const float*)d_in[9],
      (const bf16_t*)(ws + W3_OFF), (const float*)d_in[11],
      (const bf16_t*)(ws + MUW_OFF), (const float*)d_in[13],
      (float*)d_out);
}